// Round 6
// baseline (144.848 us; speedup 1.0000x reference)
//
#include <hip/hip_runtime.h>
#include <hip/hip_bf16.h>

// BertCRFTagger — B=32, S=512, H=1024, T=32.
//  K0 wpack:      W -> bf16 transposed [t][k]; 8 blocks; b0t0 zeroes out.
//  K1 emis_fused: MFMA GEMV + fused log_softmax, split-K x4 (R1, unchanged).
//  K2 chunk:      R15 (= R14 algorithm, slim envelope after 2nd container
//                 failure): per-chunk chain SPLIT INTO TWO INDEPENDENT
//                 HALVES (T_chunk = T[0..7] x T[8..15], both start from
//                 identity) run INTERLEAVED in one wave -> serial depth
//                 16 -> 8 steps. P roundtrip in bf16 (f2bf at write =
//                 bitwise-same as f32 roundtrip + convert-on-read) and
//                 ALIASED ONTO Ebuf (dead until epilogue) -> 21.6 KB LDS
//                 (was 58.4). Then 3 combine rounds: own-halves, 4->2,
//                 2->1 -> 8 super-chunks/batch. 256 blocks x 4 waves.
//  K3 phase2:     R13 sweep over 8 super-chunks (unchanged).
//  R3 lesson: latency-bound => chains spread across CUs; serial depth is
//  the currency (R13 depth 32->8 = ~10us).

#define Bb 32
#define Ss 512
#define Hh 1024
#define Tt 32
#define NROWS (Bb*Ss)          // 16384
#define NCHUNK 32
#define CHUNK_L 16
#define NSUP 8

typedef __attribute__((ext_vector_type(8))) short bf16x8;
typedef __attribute__((ext_vector_type(4))) float f32x4;

__device__ __forceinline__ short f2bf(float f) {  // RNE fp32->bf16
  union { float f; unsigned u; } v; v.f = f;
  unsigned u = v.u;
  return (short)((u + 0x7FFFu + ((u >> 16) & 1u)) >> 16);
}
__device__ __forceinline__ float bf2f(short s) {
  union { unsigned u; float f; } v;
  v.u = ((unsigned)(unsigned short)s) << 16;
  return v.f;
}

// ---------------- K0: pack W -> bf16 [t][k] + zero out ----------------
__global__ __launch_bounds__(128) void wpack_kernel(
    const float* __restrict__ W, short* __restrict__ Wpk,
    float* __restrict__ out) {
  const int k = blockIdx.x * 128 + threadIdx.x;
  if (k == 0) out[0] = 0.f;   // phase2 atomicAdds into this
#pragma unroll
  for (int t = 0; t < 32; ++t)
    Wpk[t * Hh + k] = f2bf(W[k * 32 + t]);
}

// ---------------- K1: fused MFMA emissions + log_softmax, split-K ----------
// grid 1024 x 256thr. Block = rows row0..row0+15; wave wv does K quarter wv.
// A[m=lane&15][k=(lane>>4)*8+j]; B[k][n=lane&15]; C/D col=lane&15,row=q*4+r.
// Stage layout: byte addr = wv*8192 + kc*1024 + (((n*4+q)*16) ^ (kc*32)) + j*2.
__global__ __launch_bounds__(256) void emis_fused_kernel(
    const float* __restrict__ hidden, const short* __restrict__ Wpk,
    const float* __restrict__ bias, float* __restrict__ logem) {
  __shared__ __align__(16) char smem[32768];  // stage (bf16) / red (aliased)
  float* red = (float*)smem;                  // [wave][row][col] stride 33
  const int tid = threadIdx.x;
  const int wv = tid >> 6, lane = tid & 63;
  const int n = lane & 15, q = lane >> 4;
  const int row0 = blockIdx.x * 16;
  const int koff = wv * 256;

  // ---- stage: thread t owns k0=4t of each of the 16 rows ----
  {
    const int skc = (tid >> 3) & 7;     // (k0>>5)&7
    const int sq = (tid >> 1) & 3;      // (k0>>3)&3
    const int sj0 = (tid & 1) * 4;      // k0&7
    const int rbase = (tid >> 6) * 8192 + skc * 1024 + sj0 * 2;
    const int uxor = skc * 32;
    const float* hp = hidden + (size_t)row0 * Hh + 4 * tid;
#pragma unroll
    for (int i = 0; i < 16; ++i) {
      const float4 v = *(const float4*)(hp + (size_t)i * Hh);
      uint2 u;
      u.x = (unsigned short)f2bf(v.x) | ((unsigned)(unsigned short)f2bf(v.y) << 16);
      u.y = (unsigned short)f2bf(v.z) | ((unsigned)(unsigned short)f2bf(v.w) << 16);
      const int unit = ((i * 4 + sq) * 16) ^ uxor;
      *(uint2*)(smem + rbase + unit) = u;
    }
  }
  __syncthreads();

  // ---- MFMA loop: 1 ds_read_b128 (A) + 2 global 16B (W) per kc ----
  const short* bpl = Wpk + n * Hh + koff;
  const short* bpr = Wpk + (16 + n) * Hh + koff;
  f32x4 d0 = {0.f, 0.f, 0.f, 0.f}, d1 = {0.f, 0.f, 0.f, 0.f};
#pragma unroll
  for (int kc = 0; kc < 8; ++kc) {
    const int aaddr = wv * 8192 + kc * 1024 + (((n * 4 + q) * 16) ^ (kc * 32));
    const bf16x8 a = *(const bf16x8*)(smem + aaddr);
    const bf16x8 wl = *(const bf16x8*)(bpl + kc * 32 + 8 * q);
    const bf16x8 wr = *(const bf16x8*)(bpr + kc * 32 + 8 * q);
    d0 = __builtin_amdgcn_mfma_f32_16x16x32_bf16(a, wl, d0, 0, 0, 0);
    d1 = __builtin_amdgcn_mfma_f32_16x16x32_bf16(a, wr, d1, 0, 0, 0);
  }
  __syncthreads();  // stage dead -> red may alias

  // partials -> LDS
#pragma unroll
  for (int r = 0; r < 4; ++r) {
    red[(wv * 16 + 4 * q + r) * 33 + n] = d0[r];
    red[(wv * 16 + 4 * q + r) * 33 + 16 + n] = d1[r];
  }
  __syncthreads();

  // combine + softmax: thread = (row = tid>>4, cols c0 = tid&15, c1 = c0+16).
  const int row = tid >> 4, c0 = tid & 15, c1 = 16 + c0;
  float v0 = 0.f, v1 = 0.f;
#pragma unroll
  for (int w = 0; w < 4; ++w) {
    v0 += red[(w * 16 + row) * 33 + c0];
    v1 += red[(w * 16 + row) * 33 + c1];
  }
  const float L0 = v0 + bias[c0], L1 = v1 + bias[c1];
  float mx = fmaxf(L0, L1);
#pragma unroll
  for (int d = 8; d >= 1; d >>= 1) mx = fmaxf(mx, __shfl_xor(mx, d, 16));
  float se = __expf(L0 - mx) + __expf(L1 - mx);
#pragma unroll
  for (int d = 8; d >= 1; d >>= 1) se += __shfl_xor(se, d, 16);
  const float corr = mx + __logf(se);
  const size_t rb = (size_t)(row0 + row) * Tt;
  logem[rb + c0] = L0 - corr;
  logem[rb + c1] = L1 - corr;
}

// ---- combine32: C = Ea x (Eb scaled by exp(Ob-obmax)); normalize rows. ----
// Ea/Eb: [32][40] bf16 row-major in LDS. Outputs: c** quadrants (normalized
// via iv), lgn* = new per-row offsets (= Oa[row] + obmax + log(rowmax)).
__device__ __forceinline__ void combine32(
    const short* __restrict__ Ea, const short* __restrict__ Eb,
    const float* __restrict__ Oa, const float* __restrict__ Ob, float obmax,
    int n, int q,
    f32x4& c00, f32x4& c01, f32x4& c10, f32x4& c11,
    float* __restrict__ lgn0, float* __restrict__ lgn1,
    float* __restrict__ iv0, float* __restrict__ iv1) {
  const bf16x8 a0 = *(const bf16x8*)(Ea + n * 40 + 8 * q);
  const bf16x8 a1 = *(const bf16x8*)(Ea + (16 + n) * 40 + 8 * q);
  bf16x8 bL, bR;
#pragma unroll
  for (int jj = 0; jj < 8; ++jj) {
    const float sc = __expf(Ob[8 * q + jj] - obmax);
    bL[jj] = f2bf(bf2f(Eb[(8 * q + jj) * 40 + n]) * sc);
    bR[jj] = f2bf(bf2f(Eb[(8 * q + jj) * 40 + 16 + n]) * sc);
  }
  const f32x4 z = {0.f, 0.f, 0.f, 0.f};
  c00 = __builtin_amdgcn_mfma_f32_16x16x32_bf16(a0, bL, z, 0, 0, 0);
  c01 = __builtin_amdgcn_mfma_f32_16x16x32_bf16(a0, bR, z, 0, 0, 0);
  c10 = __builtin_amdgcn_mfma_f32_16x16x32_bf16(a1, bL, z, 0, 0, 0);
  c11 = __builtin_amdgcn_mfma_f32_16x16x32_bf16(a1, bR, z, 0, 0, 0);
#pragma unroll
  for (int r = 0; r < 4; ++r) {
    float m0v = fmaxf(c00[r], c01[r]);
    float m1v = fmaxf(c10[r], c11[r]);
#pragma unroll
    for (int d = 8; d >= 1; d >>= 1) {
      m0v = fmaxf(m0v, __shfl_xor(m0v, d, 16));
      m1v = fmaxf(m1v, __shfl_xor(m1v, d, 16));
    }
    m0v = fmaxf(m0v, 1e-37f);
    m1v = fmaxf(m1v, 1e-37f);
    iv0[r] = __builtin_amdgcn_rcpf(m0v);
    iv1[r] = __builtin_amdgcn_rcpf(m1v);
    lgn0[r] = Oa[4 * q + r] + obmax + __logf(m0v);
    lgn1[r] = Oa[16 + 4 * q + r] + obmax + __logf(m1v);
  }
}

// ---- half epilogue: normalize a half-chain product into LDS bf16 + offs ---
// E may alias the chain's P-buffer: all sources are registers, no P reads.
__device__ __forceinline__ void half_epilogue(
    f32x4 d00, f32x4 d01, f32x4 d10, f32x4 d11, int nst,
    int n, int q, int lane, short* __restrict__ E,
    float* __restrict__ O, float* __restrict__ cmxp) {
  if (nst == 0) {
#pragma unroll
    for (int r = 0; r < 4; ++r) {
      d00[r] = (4 * q + r == n) ? 1.f : 0.f;
      d01[r] = 0.f;
      d10[r] = 0.f;
      d11[r] = (4 * q + r == n) ? 1.f : 0.f;
    }
  }
  float lg0[4], lg1[4], iv0[4], iv1[4];
#pragma unroll
  for (int r = 0; r < 4; ++r) {
    float m0v = fmaxf(d00[r], d01[r]);
    float m1v = fmaxf(d10[r], d11[r]);
#pragma unroll
    for (int d = 8; d >= 1; d >>= 1) {
      m0v = fmaxf(m0v, __shfl_xor(m0v, d, 16));
      m1v = fmaxf(m1v, __shfl_xor(m1v, d, 16));
    }
    m0v = fmaxf(m0v, 1e-37f);
    m1v = fmaxf(m1v, 1e-37f);
    lg0[r] = __logf(m0v); iv0[r] = __builtin_amdgcn_rcpf(m0v);
    lg1[r] = __logf(m1v); iv1[r] = __builtin_amdgcn_rcpf(m1v);
  }
#pragma unroll
  for (int r = 0; r < 4; ++r) {
    E[(4 * q + r) * 40 + n] = f2bf(d00[r] * iv0[r]);
    E[(4 * q + r) * 40 + 16 + n] = f2bf(d01[r] * iv0[r]);
    E[(16 + 4 * q + r) * 40 + n] = f2bf(d10[r] * iv1[r]);
    E[(16 + 4 * q + r) * 40 + 16 + n] = f2bf(d11[r] * iv1[r]);
  }
  if (n == 0) {
#pragma unroll
    for (int r = 0; r < 4; ++r) {
      O[4 * q + r] = lg0[r];
      O[16 + 4 * q + r] = lg1[r];
    }
  }
  float cm = fmaxf(fmaxf(fmaxf(lg0[0], lg0[1]), fmaxf(lg0[2], lg0[3])),
                   fmaxf(fmaxf(lg1[0], lg1[1]), fmaxf(lg1[2], lg1[3])));
  cm = fmaxf(cm, __shfl_xor(cm, 16));
  cm = fmaxf(cm, __shfl_xor(cm, 32));
  if (lane == 0) *cmxp = cm;
}

// ---------------- K2: dual half-chains + 3-round combine tree --------------
// 256 blocks x 256 thr. Wave wv owns chunk = blockIdx*4+wv, run as TWO
// interleaved 8-step half-chains (independent, both start from identity);
// bf16 P roundtrip ALIASED onto Ebuf (dead until epilogue). Tree:
// own-halves -> chunk; 4->2; 2->1 super per block. 21.6 KB LDS.
__global__ __launch_bounds__(256) void chunk_kernel(
    const float* __restrict__ logem, const float* __restrict__ trans,
    const int* __restrict__ mask, float* __restrict__ ecT4,
    float* __restrict__ moff4, float* __restrict__ cmax4) {
  __shared__ __align__(16) short Ebuf[4][2][32][40];  // 20.5 KB: P / half mats
  __shared__ float Obuf[4][2][32];                    // per-row offsets
  __shared__ float Cmx[4][2];                         // per-matrix max off
  const int tid = threadIdx.x;
  const int wv = tid >> 6, lane = tid & 63;
  const int n = lane & 15, q = lane >> 4;
  const int chunk = blockIdx.x * 4 + wv;
  const int b = chunk >> 5, cc = chunk & 31;
  short* PA = &Ebuf[wv][0][0][0];   // chain-phase alias
  short* PB = &Ebuf[wv][1][0][0];

  float etr0[8], etr1[8];
#pragma unroll
  for (int jj = 0; jj < 8; ++jj) {
    etr0[jj] = __expf(trans[(8 * q + jj) * 32 + n]);
    etr1[jj] = __expf(trans[(8 * q + jj) * 32 + 16 + n]);
  }

  const int t0 = 1 + cc * CHUNK_L;
  const int rowbase = b * Ss + t0;      // half A rows: rowbase+st
  const int rowbaseB = rowbase + 8;     // half B rows: rowbaseB+st
  int pred = 0;
  if (lane < 16 && t0 + lane < Ss) pred = mask[rowbase + lane];
  const unsigned long long bal = __ballot(pred != 0);
  const int nst = __popcll(bal & 0xFFFFull);
  const int nstA = nst < 8 ? nst : 8;
  const int nstB = nst > 8 ? nst - 8 : 0;

  bf16x8 aA0, aA1, aB0, aB1;
#pragma unroll
  for (int jj = 0; jj < 8; ++jj) {
    const short ilo = (n == 8 * q + jj) ? (short)0x3F80 : (short)0;
    const short ihi = (16 + n == 8 * q + jj) ? (short)0x3F80 : (short)0;
    aA0[jj] = ilo; aA1[jj] = ihi;
    aB0[jj] = ilo; aB1[jj] = ihi;
  }

  f32x4 dA00 = {0,0,0,0}, dA01 = {0,0,0,0}, dA10 = {0,0,0,0}, dA11 = {0,0,0,0};
  f32x4 dB00 = {0,0,0,0}, dB01 = {0,0,0,0}, dB10 = {0,0,0,0}, dB11 = {0,0,0,0};

  float emA0 = 0.f, emA1 = 0.f, emB0 = 0.f, emB1 = 0.f;
  if (nstA > 0) {
    emA0 = __expf(logem[(size_t)rowbase * Tt + n]);
    emA1 = __expf(logem[(size_t)rowbase * Tt + 16 + n]);
  }
  if (nstB > 0) {
    emB0 = __expf(logem[(size_t)rowbaseB * Tt + n]);
    emB1 = __expf(logem[(size_t)rowbaseB * Tt + 16 + n]);
  }

  const int nmax = nstA > nstB ? nstA : nstB;
  for (int st = 0; st < nmax; ++st) {
    float emA0n = 0.f, emA1n = 0.f, emB0n = 0.f, emB1n = 0.f;
    if (st + 1 < nstA) {
      emA0n = __expf(logem[(size_t)(rowbase + st + 1) * Tt + n]);
      emA1n = __expf(logem[(size_t)(rowbase + st + 1) * Tt + 16 + n]);
    }
    if (st + 1 < nstB) {
      emB0n = __expf(logem[(size_t)(rowbaseB + st + 1) * Tt + n]);
      emB1n = __expf(logem[(size_t)(rowbaseB + st + 1) * Tt + 16 + n]);
    }
    const f32x4 z = {0.f, 0.f, 0.f, 0.f};
    if (st < nstA) {
      bf16x8 bL, bR;
#pragma unroll
      for (int jj = 0; jj < 8; ++jj) {
        bL[jj] = f2bf(etr0[jj] * emA0);
        bR[jj] = f2bf(etr1[jj] * emA1);
      }
      dA00 = __builtin_amdgcn_mfma_f32_16x16x32_bf16(aA0, bL, z, 0, 0, 0);
      dA01 = __builtin_amdgcn_mfma_f32_16x16x32_bf16(aA0, bR, z, 0, 0, 0);
      dA10 = __builtin_amdgcn_mfma_f32_16x16x32_bf16(aA1, bL, z, 0, 0, 0);
      dA11 = __builtin_amdgcn_mfma_f32_16x16x32_bf16(aA1, bR, z, 0, 0, 0);
    }
    if (st < nstB) {
      bf16x8 bL, bR;
#pragma unroll
      for (int jj = 0; jj < 8; ++jj) {
        bL[jj] = f2bf(etr0[jj] * emB0);
        bR[jj] = f2bf(etr1[jj] * emB1);
      }
      dB00 = __builtin_amdgcn_mfma_f32_16x16x32_bf16(aB0, bL, z, 0, 0, 0);
      dB01 = __builtin_amdgcn_mfma_f32_16x16x32_bf16(aB0, bR, z, 0, 0, 0);
      dB10 = __builtin_amdgcn_mfma_f32_16x16x32_bf16(aB1, bL, z, 0, 0, 0);
      dB11 = __builtin_amdgcn_mfma_f32_16x16x32_bf16(aB1, bR, z, 0, 0, 0);
    }
    const bool wA = (st + 1 < nstA), wB = (st + 1 < nstB);
    if (wA) {   // bf16 write = f2bf(d); read-back identical to f32 roundtrip
#pragma unroll
      for (int r = 0; r < 4; ++r) {
        PA[(4 * q + r) * 40 + n] = f2bf(dA00[r]);
        PA[(4 * q + r) * 40 + 16 + n] = f2bf(dA01[r]);
        PA[(16 + 4 * q + r) * 40 + n] = f2bf(dA10[r]);
        PA[(16 + 4 * q + r) * 40 + 16 + n] = f2bf(dA11[r]);
      }
    }
    if (wB) {
#pragma unroll
      for (int r = 0; r < 4; ++r) {
        PB[(4 * q + r) * 40 + n] = f2bf(dB00[r]);
        PB[(4 * q + r) * 40 + 16 + n] = f2bf(dB01[r]);
        PB[(16 + 4 * q + r) * 40 + n] = f2bf(dB10[r]);
        PB[(16 + 4 * q + r) * 40 + 16 + n] = f2bf(dB11[r]);
      }
    }
    if (wA | wB) {
      asm volatile("s_waitcnt lgkmcnt(0)" ::: "memory");  // LDS roundtrip only
      __builtin_amdgcn_sched_barrier(0);                  // em loads in flight
    }
    if (wA) {
      aA0 = *(const bf16x8*)(PA + n * 40 + 8 * q);
      aA1 = *(const bf16x8*)(PA + (16 + n) * 40 + 8 * q);
    }
    if (wB) {
      aB0 = *(const bf16x8*)(PB + n * 40 + 8 * q);
      aB1 = *(const bf16x8*)(PB + (16 + n) * 40 + 8 * q);
    }
    emA0 = emA0n; emA1 = emA1n; emB0 = emB0n; emB1 = emB1n;
  }

  half_epilogue(dA00, dA01, dA10, dA11, nstA, n, q, lane,
                &Ebuf[wv][0][0][0], Obuf[wv][0], &Cmx[wv][0]);
  half_epilogue(dB00, dB01, dB10, dB11, nstB, n, q, lane,
                &Ebuf[wv][1][0][0], Obuf[wv][1], &Cmx[wv][1]);
  __syncthreads();

  // ---- round 0: own halves -> chunk matrix (slot [wv][0]) ----
  {
    f32x4 c00, c01, c10, c11;
    float lg0[4], lg1[4], iv0[4], iv1[4];
    combine32(&Ebuf[wv][0][0][0], &Ebuf[wv][1][0][0],
              Obuf[wv][0], Obuf[wv][1], Cmx[wv][1],
              n, q, c00, c01, c10, c11, lg0, lg1, iv0, iv1);
#pragma unroll
    for (int r = 0; r < 4; ++r) {
      Ebuf[wv][0][4 * q + r][n] = f2bf(c00[r] * iv0[r]);
      Ebuf[wv][0][4 * q + r][16 + n] = f2bf(c01[r] * iv0[r]);
      Ebuf[wv][0][16 + 4 * q + r][n] = f2bf(c10[r] * iv1[r]);
      Ebuf[wv][0][16 + 4 * q + r][16 + n] = f2bf(c11[r] * iv1[r]);
    }
    if (n == 0) {
#pragma unroll
      for (int r = 0; r < 4; ++r) {
        Obuf[wv][0][4 * q + r] = lg0[r];
        Obuf[wv][0][16 + 4 * q + r] = lg1[r];
      }
    }
    float cm = fmaxf(fmaxf(fmaxf(lg0[0], lg0[1]), fmaxf(lg0[2], lg0[3])),
                     fmaxf(fmaxf(lg1[0], lg1[1]), fmaxf(lg1[2], lg1[3])));
    cm = fmaxf(cm, __shfl_xor(cm, 16));
    cm = fmaxf(cm, __shfl_xor(cm, 32));
    if (lane == 0) Cmx[wv][0] = cm;
  }
  __syncthreads();

  // ---- round 1: wv0: T01 -> [0][0]; wv1: T23 -> [2][0] ----
  if (wv < 2) {
    const int ai = 2 * wv, bi = 2 * wv + 1;
    f32x4 c00, c01, c10, c11;
    float lg0[4], lg1[4], iv0[4], iv1[4];
    combine32(&Ebuf[ai][0][0][0], &Ebuf[bi][0][0][0],
              Obuf[ai][0], Obuf[bi][0], Cmx[bi][0],
              n, q, c00, c01, c10, c11, lg0, lg1, iv0, iv1);
#pragma unroll
    for (int r = 0; r < 4; ++r) {
      Ebuf[ai][0][4 * q + r][n] = f2bf(c00[r] * iv0[r]);
      Ebuf[ai][0][4 * q + r][16 + n] = f2bf(c01[r] * iv0[r]);
      Ebuf[ai][0][16 + 4 * q + r][n] = f2bf(c10[r] * iv1[r]);
      Ebuf[ai][0][16 + 4 * q + r][16 + n] = f2bf(c11[r] * iv1[r]);
    }
    if (n == 0) {
#pragma unroll
      for (int r = 0; r < 4; ++r) {
        Obuf[ai][0][4 * q + r] = lg0[r];
        Obuf[ai][0][16 + 4 * q + r] = lg1[r];
      }
    }
    float cm = fmaxf(fmaxf(fmaxf(lg0[0], lg0[1]), fmaxf(lg0[2], lg0[3])),
                     fmaxf(fmaxf(lg1[0], lg1[1]), fmaxf(lg1[2], lg1[3])));
    cm = fmaxf(cm, __shfl_xor(cm, 16));
    cm = fmaxf(cm, __shfl_xor(cm, 32));
    if (lane == 0) Cmx[ai][0] = cm;
  }
  __syncthreads();

  // ---- round 2: wv0: T0123 -> global super matrix ----
  if (wv == 0) {
    f32x4 c00, c01, c10, c11;
    float lg0[4], lg1[4], iv0[4], iv1[4];
    combine32(&Ebuf[0][0][0][0], &Ebuf[2][0][0][0],
              Obuf[0][0], Obuf[2][0], Cmx[2][0],
              n, q, c00, c01, c10, c11, lg0, lg1, iv0, iv1);
    const int sup = blockIdx.x;  // = b*NSUP + s
    float* E = ecT4 + (size_t)sup * 32 * 32;
    {
      float4 s;
      s = make_float4(c00[0] * iv0[0], c00[1] * iv0[1], c00[2] * iv0[2], c00[3] * iv0[3]);
      *(float4*)&E[n * 32 + 4 * q] = s;
      s = make_float4(c10[0] * iv1[0], c10[1] * iv1[1], c10[2] * iv1[2], c10[3] * iv1[3]);
      *(float4*)&E[n * 32 + 16 + 4 * q] = s;
      s = make_float4(c01[0] * iv0[0], c01[1] * iv0[1], c01[2] * iv0[2], c01[3] * iv0[3]);
      *(float4*)&E[(16 + n) * 32 + 4 * q] = s;
      s = make_float4(c11[0] * iv1[0], c11[1] * iv1[1], c11[2] * iv1[2], c11[3] * iv1[3]);
      *(float4*)&E[(16 + n) * 32 + 16 + 4 * q] = s;
    }
    if (n == 0) {
      float* Mo = moff4 + (size_t)sup * 32;
      *(float4*)&Mo[4 * q] = make_float4(lg0[0], lg0[1], lg0[2], lg0[3]);
      *(float4*)&Mo[16 + 4 * q] = make_float4(lg1[0], lg1[1], lg1[2], lg1[3]);
    }
    float cm = fmaxf(fmaxf(fmaxf(lg0[0], lg0[1]), fmaxf(lg0[2], lg0[3])),
                     fmaxf(fmaxf(lg1[0], lg1[1]), fmaxf(lg1[2], lg1[3])));
    cm = fmaxf(cm, __shfl_xor(cm, 16));
    cm = fmaxf(cm, __shfl_xor(cm, 32));
    if (lane == 0) cmax4[sup] = cm;
  }
}

// ---------------- K3: phase-2 sweep (8 supers) + fused numerator -----------
__global__ __launch_bounds__(64) void phase2_kernel(
    const float* __restrict__ logem, const float* __restrict__ start_trans,
    const float* __restrict__ end_trans, const float* __restrict__ ecT4,
    const float* __restrict__ moff4, const float* __restrict__ cmax4,
    const float* __restrict__ trans, const int* __restrict__ tags,
    const int* __restrict__ mask, float* __restrict__ out) {
  const int b = blockIdx.x;
  const int lane = threadIdx.x;
  const int j = lane & 31;
  __shared__ __align__(16) float qlds[32];

  const int base_row = b * Ss;
  int lensum = 0;
  float snum = 0.f;
#pragma unroll
  for (int k = 0; k < 8; ++k) {
    const int ss = lane + 64 * k;
    const int m = mask[base_row + ss];
    lensum += m;
    if (m) {
      const int tg = tags[base_row + ss];
      snum += logem[(size_t)(base_row + ss) * Tt + tg];
      if (ss > 0) snum += trans[tags[base_row + ss - 1] * Tt + tg];
    }
  }
#pragma unroll
  for (int d = 32; d >= 1; d >>= 1) {
    snum += __shfl_xor(snum, d);
    lensum += __shfl_xor(lensum, d);
  }

  const float* base = ecT4 + (size_t)b * NSUP * 32 * 32;
  const float* mbase = moff4 + (size_t)b * NSUP * 32;
  const float cm_l = (j < NSUP) ? cmax4[b * NSUP + j] : 0.f;

  float4 M[8], N[8];
  const float* r0 = base + j * 32;
#pragma unroll
  for (int k = 0; k < 8; ++k) M[k] = *(const float4*)(r0 + 4 * k);
  float mo_cur = mbase[j];

  float al0 = start_trans[j] + logem[(size_t)base_row * Tt + j];
  float m0 = al0;
#pragma unroll
  for (int d = 16; d >= 1; d >>= 1) m0 = fmaxf(m0, __shfl_xor(m0, d, 32));
  float a = __expf(al0 - m0);
  float Mb = m0;
  const float eend = __expf(end_trans[j]);

  float mo_next = 0.f;
  for (int c = 0; c < NSUP; ++c) {
    if (c + 1 < NSUP) {
      const float* rn = base + ((c + 1) * 32 + j) * 32;
#pragma unroll
      for (int k = 0; k < 8; ++k) N[k] = *(const float4*)(rn + 4 * k);
      mo_next = mbase[(c + 1) * 32 + j];
    }
    const float mom = __shfl(cm_l, c, 32);   // uniform broadcast, no reduce
    const float qv = a * __expf(mo_cur - mom);
    if (lane < 32) qlds[j] = qv;
    asm volatile("s_waitcnt lgkmcnt(0)" ::: "memory");  // LDS only; ecT4
    __builtin_amdgcn_sched_barrier(0);                  // prefetch stays in flight
    float s0 = 0.f, s1 = 0.f, s2 = 0.f, s3 = 0.f;       // depth-8 chains
#pragma unroll
    for (int k = 0; k < 8; ++k) {
      const float4 q4 = *(const float4*)(qlds + 4 * k);
      float* sp = (k & 1) ? ((k & 2) ? &s3 : &s1) : ((k & 2) ? &s2 : &s0);
      *sp = fmaf(q4.x, M[k].x, *sp);
      *sp = fmaf(q4.y, M[k].y, *sp);
      *sp = fmaf(q4.z, M[k].z, *sp);
      *sp = fmaf(q4.w, M[k].w, *sp);
    }
    const float s = (s0 + s1) + (s2 + s3);
    Mb += mom;
    if ((c & 3) == 3) {        // rescale at c=3,7 (exact: skipped log factors
      float m = s;             // ride inside a until here; f32 headroom ok)
#pragma unroll
      for (int d = 16; d >= 1; d >>= 1) m = fmaxf(m, __shfl_xor(m, d, 32));
      m = fmaxf(m, 1e-30f);
      a = s * __builtin_amdgcn_rcpf(m);
      Mb += __logf(m);
    } else {
      a = s;
    }
#pragma unroll
    for (int k = 0; k < 8; ++k) M[k] = N[k];
    mo_cur = mo_next;
  }
  float z = a * eend;
#pragma unroll
  for (int d = 16; d >= 1; d >>= 1) z += __shfl_xor(z, d, 32);
  if (lane == 0) {
    const float numfull = snum + start_trans[tags[base_row]] +
                          end_trans[tags[base_row + lensum - 1]];
    const float denom = Mb + __logf(z);
    atomicAdd(out, -(numfull - denom) * (1.0f / 32.0f));
  }
}

extern "C" void kernel_launch(void* const* d_in, const int* in_sizes, int n_in,
                              void* d_out, int out_size, void* d_ws, size_t ws_size,
                              hipStream_t stream) {
  const float* hidden = (const float*)d_in[0];
  const float* W = (const float*)d_in[1];
  const float* bias = (const float*)d_in[2];
  const float* start_trans = (const float*)d_in[3];
  const float* end_trans = (const float*)d_in[4];
  const float* trans = (const float*)d_in[5];
  const int* tags = (const int*)d_in[6];
  const int* mask = (const int*)d_in[7];
  float* out = (float*)d_out;

  float* logem = (float*)d_ws;                          // 2 MB
  float* ecT4 = logem + (size_t)NROWS * Tt;             // 1 MB
  float* moff4 = ecT4 + (size_t)Bb * NSUP * 32 * 32;    // 32 KB
  float* cmax4 = moff4 + (size_t)Bb * NSUP * 32;        // 1 KB
  short* Wpk = (short*)(cmax4 + (size_t)Bb * NSUP);     // 64 KB

  wpack_kernel<<<8, 128, 0, stream>>>(W, Wpk, out);  // also zeroes out
  emis_fused_kernel<<<NROWS / 16, 256, 0, stream>>>(hidden, Wpk, bias, logem);
  chunk_kernel<<<Bb * NCHUNK / 4, 256, 0, stream>>>(logem, trans, mask,
                                                    ecT4, moff4, cmax4);
  phase2_kernel<<<Bb, 64, 0, stream>>>(logem, start_trans, end_trans, ecT4,
                                       moff4, cmax4, trans, tags, mask, out);
}

// Round 7
// 140.178 us; speedup vs baseline: 1.0333x; 1.0333x over previous
//
#include <hip/hip_runtime.h>
#include <hip/hip_bf16.h>

// BertCRFTagger — B=32, S=512, H=1024, T=32.
//  K0 wpack:      W -> bf16 transposed [t][k]; 8 blocks; b0t0 zeroes out.
//  K1 emis_fused: MFMA GEMV + fused log_softmax, split-K x4 (R1, unchanged).
//  K2 chunk:      R1 chain phase (256 blocks, 1 chunk/wave, full parallelism)
//                 + R13 in-block combine tree: each block's 4 consecutive
//                 chunk matrices are combined 4->1 via 2 MFMA rounds
//                 (T01=T0xT1, T23=T2xT3; T0123=T01xT23) with offset
//                 composition o_new[i] = o_a[i] + max(o_b) + log(rowmax).
//                 Writes 8 super-chunk matrices per batch (1MB vs 4MB).
//  K3 phase2:     R1 sweep but over 8 super-chunks (serial depth 32 -> 8).
//  R16 = R13 revert (measured best 141.4us). R14/R15 dual-half chain did
//  not beat it (144.8); R12 fusion regressed (60us @1.65% occupancy).
//  Composed floor ~140-142us: 123us harness fills + 10.2us K1 HBM floor +
//  ~6us serial CRF + launches. At floor -> roofline if reproduced.

#define Bb 32
#define Ss 512
#define Hh 1024
#define Tt 32
#define NROWS (Bb*Ss)          // 16384
#define NCHUNK 32
#define CHUNK_L 16
#define NSUP 8

typedef __attribute__((ext_vector_type(8))) short bf16x8;
typedef __attribute__((ext_vector_type(4))) float f32x4;

__device__ __forceinline__ short f2bf(float f) {  // RNE fp32->bf16
  union { float f; unsigned u; } v; v.f = f;
  unsigned u = v.u;
  return (short)((u + 0x7FFFu + ((u >> 16) & 1u)) >> 16);
}
__device__ __forceinline__ float bf2f(short s) {
  union { unsigned u; float f; } v;
  v.u = ((unsigned)(unsigned short)s) << 16;
  return v.f;
}

// ---------------- K0: pack W -> bf16 [t][k] + zero out ----------------
__global__ __launch_bounds__(128) void wpack_kernel(
    const float* __restrict__ W, short* __restrict__ Wpk,
    float* __restrict__ out) {
  const int k = blockIdx.x * 128 + threadIdx.x;
  if (k == 0) out[0] = 0.f;   // phase2 atomicAdds into this
#pragma unroll
  for (int t = 0; t < 32; ++t)
    Wpk[t * Hh + k] = f2bf(W[k * 32 + t]);
}

// ---------------- K1: fused MFMA emissions + log_softmax, split-K ----------
// grid 1024 x 256thr. Block = rows row0..row0+15; wave wv does K quarter wv.
// A[m=lane&15][k=(lane>>4)*8+j]; B[k][n=lane&15]; C/D col=lane&15,row=q*4+r.
// Stage layout: byte addr = wv*8192 + kc*1024 + (((n*4+q)*16) ^ (kc*32)) + j*2.
__global__ __launch_bounds__(256) void emis_fused_kernel(
    const float* __restrict__ hidden, const short* __restrict__ Wpk,
    const float* __restrict__ bias, float* __restrict__ logem) {
  __shared__ __align__(16) char smem[32768];  // stage (bf16) / red (aliased)
  float* red = (float*)smem;                  // [wave][row][col] stride 33
  const int tid = threadIdx.x;
  const int wv = tid >> 6, lane = tid & 63;
  const int n = lane & 15, q = lane >> 4;
  const int row0 = blockIdx.x * 16;
  const int koff = wv * 256;

  // ---- stage: thread t owns k0=4t of each of the 16 rows ----
  {
    const int skc = (tid >> 3) & 7;     // (k0>>5)&7
    const int sq = (tid >> 1) & 3;      // (k0>>3)&3
    const int sj0 = (tid & 1) * 4;      // k0&7
    const int rbase = (tid >> 6) * 8192 + skc * 1024 + sj0 * 2;
    const int uxor = skc * 32;
    const float* hp = hidden + (size_t)row0 * Hh + 4 * tid;
#pragma unroll
    for (int i = 0; i < 16; ++i) {
      const float4 v = *(const float4*)(hp + (size_t)i * Hh);
      uint2 u;
      u.x = (unsigned short)f2bf(v.x) | ((unsigned)(unsigned short)f2bf(v.y) << 16);
      u.y = (unsigned short)f2bf(v.z) | ((unsigned)(unsigned short)f2bf(v.w) << 16);
      const int unit = ((i * 4 + sq) * 16) ^ uxor;
      *(uint2*)(smem + rbase + unit) = u;
    }
  }
  __syncthreads();

  // ---- MFMA loop: 1 ds_read_b128 (A) + 2 global 16B (W) per kc ----
  const short* bpl = Wpk + n * Hh + koff;
  const short* bpr = Wpk + (16 + n) * Hh + koff;
  f32x4 d0 = {0.f, 0.f, 0.f, 0.f}, d1 = {0.f, 0.f, 0.f, 0.f};
#pragma unroll
  for (int kc = 0; kc < 8; ++kc) {
    const int aaddr = wv * 8192 + kc * 1024 + (((n * 4 + q) * 16) ^ (kc * 32));
    const bf16x8 a = *(const bf16x8*)(smem + aaddr);
    const bf16x8 wl = *(const bf16x8*)(bpl + kc * 32 + 8 * q);
    const bf16x8 wr = *(const bf16x8*)(bpr + kc * 32 + 8 * q);
    d0 = __builtin_amdgcn_mfma_f32_16x16x32_bf16(a, wl, d0, 0, 0, 0);
    d1 = __builtin_amdgcn_mfma_f32_16x16x32_bf16(a, wr, d1, 0, 0, 0);
  }
  __syncthreads();  // stage dead -> red may alias

  // partials -> LDS
#pragma unroll
  for (int r = 0; r < 4; ++r) {
    red[(wv * 16 + 4 * q + r) * 33 + n] = d0[r];
    red[(wv * 16 + 4 * q + r) * 33 + 16 + n] = d1[r];
  }
  __syncthreads();

  // combine + softmax: thread = (row = tid>>4, cols c0 = tid&15, c1 = c0+16).
  const int row = tid >> 4, c0 = tid & 15, c1 = 16 + c0;
  float v0 = 0.f, v1 = 0.f;
#pragma unroll
  for (int w = 0; w < 4; ++w) {
    v0 += red[(w * 16 + row) * 33 + c0];
    v1 += red[(w * 16 + row) * 33 + c1];
  }
  const float L0 = v0 + bias[c0], L1 = v1 + bias[c1];
  float mx = fmaxf(L0, L1);
#pragma unroll
  for (int d = 8; d >= 1; d >>= 1) mx = fmaxf(mx, __shfl_xor(mx, d, 16));
  float se = __expf(L0 - mx) + __expf(L1 - mx);
#pragma unroll
  for (int d = 8; d >= 1; d >>= 1) se += __shfl_xor(se, d, 16);
  const float corr = mx + __logf(se);
  const size_t rb = (size_t)(row0 + row) * Tt;
  logem[rb + c0] = L0 - corr;
  logem[rb + c1] = L1 - corr;
}

// ---- combine32: C = Ea x (Eb scaled by exp(Ob-obmax)); normalize rows. ----
// Ea/Eb: [32][40] bf16 row-major in LDS. Outputs: c** quadrants (normalized
// via iv), lgn* = new per-row offsets (= Oa[row] + obmax + log(rowmax)).
__device__ __forceinline__ void combine32(
    const short* __restrict__ Ea, const short* __restrict__ Eb,
    const float* __restrict__ Oa, const float* __restrict__ Ob, float obmax,
    int n, int q,
    f32x4& c00, f32x4& c01, f32x4& c10, f32x4& c11,
    float* __restrict__ lgn0, float* __restrict__ lgn1,
    float* __restrict__ iv0, float* __restrict__ iv1) {
  const bf16x8 a0 = *(const bf16x8*)(Ea + n * 40 + 8 * q);
  const bf16x8 a1 = *(const bf16x8*)(Ea + (16 + n) * 40 + 8 * q);
  bf16x8 bL, bR;
#pragma unroll
  for (int jj = 0; jj < 8; ++jj) {
    const float sc = __expf(Ob[8 * q + jj] - obmax);
    bL[jj] = f2bf(bf2f(Eb[(8 * q + jj) * 40 + n]) * sc);
    bR[jj] = f2bf(bf2f(Eb[(8 * q + jj) * 40 + 16 + n]) * sc);
  }
  const f32x4 z = {0.f, 0.f, 0.f, 0.f};
  c00 = __builtin_amdgcn_mfma_f32_16x16x32_bf16(a0, bL, z, 0, 0, 0);
  c01 = __builtin_amdgcn_mfma_f32_16x16x32_bf16(a0, bR, z, 0, 0, 0);
  c10 = __builtin_amdgcn_mfma_f32_16x16x32_bf16(a1, bL, z, 0, 0, 0);
  c11 = __builtin_amdgcn_mfma_f32_16x16x32_bf16(a1, bR, z, 0, 0, 0);
#pragma unroll
  for (int r = 0; r < 4; ++r) {
    float m0v = fmaxf(c00[r], c01[r]);
    float m1v = fmaxf(c10[r], c11[r]);
#pragma unroll
    for (int d = 8; d >= 1; d >>= 1) {
      m0v = fmaxf(m0v, __shfl_xor(m0v, d, 16));
      m1v = fmaxf(m1v, __shfl_xor(m1v, d, 16));
    }
    m0v = fmaxf(m0v, 1e-37f);
    m1v = fmaxf(m1v, 1e-37f);
    iv0[r] = __builtin_amdgcn_rcpf(m0v);
    iv1[r] = __builtin_amdgcn_rcpf(m1v);
    lgn0[r] = Oa[4 * q + r] + obmax + __logf(m0v);
    lgn1[r] = Oa[16 + 4 * q + r] + obmax + __logf(m1v);
  }
}

// ---------------- K2: chunk chains + in-block 4->1 combine tree ------------
// 256 blocks x 256 thr. Wave wv owns chunk = blockIdx*4+wv (R1 chain).
// Then: round1 (wv 0,1): T01, T23; round2 (wv 0): T0123 -> global super.
__global__ __launch_bounds__(256) void chunk_kernel(
    const float* __restrict__ logem, const float* __restrict__ trans,
    const int* __restrict__ mask, float* __restrict__ ecT4,
    float* __restrict__ moff4, float* __restrict__ cmax4) {
  __shared__ __align__(16) float Pbuf[4][32 * 36];   // chain roundtrip
  __shared__ __align__(16) short Ebuf[4][32][40];    // normalized chunk mats
  __shared__ float Obuf[4][32];                      // per-row offsets
  __shared__ float Cmx[4];                           // per-matrix max offset
  const int tid = threadIdx.x;
  const int wv = tid >> 6, lane = tid & 63;
  const int n = lane & 15, q = lane >> 4;
  const int chunk = blockIdx.x * 4 + wv;
  const int b = chunk >> 5, cc = chunk & 31;
  float* P = &Pbuf[wv][0];

  float etr0[8], etr1[8];
#pragma unroll
  for (int jj = 0; jj < 8; ++jj) {
    etr0[jj] = __expf(trans[(8 * q + jj) * 32 + n]);
    etr1[jj] = __expf(trans[(8 * q + jj) * 32 + 16 + n]);
  }

  const int t0 = 1 + cc * CHUNK_L;
  const int rowbase = b * Ss + t0;
  int pred = 0;
  if (lane < 16 && t0 + lane < Ss) pred = mask[rowbase + lane];
  const unsigned long long bal = __ballot(pred != 0);
  const int nst = __popcll(bal & 0xFFFFull);

  bf16x8 a0, a1;
#pragma unroll
  for (int jj = 0; jj < 8; ++jj) {
    a0[jj] = (n == 8 * q + jj) ? (short)0x3F80 : (short)0;
    a1[jj] = (16 + n == 8 * q + jj) ? (short)0x3F80 : (short)0;
  }

  f32x4 d00, d01, d10, d11;
  if (nst == 0) {
#pragma unroll
    for (int r = 0; r < 4; ++r) {
      d00[r] = (4 * q + r == n) ? 1.f : 0.f;
      d01[r] = 0.f;
      d10[r] = 0.f;
      d11[r] = (4 * q + r == n) ? 1.f : 0.f;
    }
  }
  float em0 = 0.f, em1 = 0.f;
  if (nst > 0) {
    em0 = __expf(logem[(size_t)rowbase * Tt + n]);
    em1 = __expf(logem[(size_t)rowbase * Tt + 16 + n]);
  }
  for (int st = 0; st < nst; ++st) {
    float em0n = 0.f, em1n = 0.f;
    if (st + 1 < nst) {
      em0n = __expf(logem[(size_t)(rowbase + st + 1) * Tt + n]);
      em1n = __expf(logem[(size_t)(rowbase + st + 1) * Tt + 16 + n]);
    }
    bf16x8 bL, bR;
#pragma unroll
    for (int jj = 0; jj < 8; ++jj) {
      bL[jj] = f2bf(etr0[jj] * em0);
      bR[jj] = f2bf(etr1[jj] * em1);
    }
    const f32x4 z = {0.f, 0.f, 0.f, 0.f};
    d00 = __builtin_amdgcn_mfma_f32_16x16x32_bf16(a0, bL, z, 0, 0, 0);
    d01 = __builtin_amdgcn_mfma_f32_16x16x32_bf16(a0, bR, z, 0, 0, 0);
    d10 = __builtin_amdgcn_mfma_f32_16x16x32_bf16(a1, bL, z, 0, 0, 0);
    d11 = __builtin_amdgcn_mfma_f32_16x16x32_bf16(a1, bR, z, 0, 0, 0);
    if (st + 1 < nst) {
#pragma unroll
      for (int r = 0; r < 4; ++r) {
        P[(4 * q + r) * 36 + n] = d00[r];
        P[(4 * q + r) * 36 + 16 + n] = d01[r];
        P[(16 + 4 * q + r) * 36 + n] = d10[r];
        P[(16 + 4 * q + r) * 36 + 16 + n] = d11[r];
      }
      asm volatile("s_waitcnt lgkmcnt(0)" ::: "memory");  // LDS roundtrip only
      __builtin_amdgcn_sched_barrier(0);                  // em loads stay in flight
      const float4 lo0 = *(const float4*)&P[n * 36 + 8 * q];
      const float4 lo1 = *(const float4*)&P[n * 36 + 8 * q + 4];
      const float4 hi0 = *(const float4*)&P[(16 + n) * 36 + 8 * q];
      const float4 hi1 = *(const float4*)&P[(16 + n) * 36 + 8 * q + 4];
      a0[0] = f2bf(lo0.x); a0[1] = f2bf(lo0.y); a0[2] = f2bf(lo0.z); a0[3] = f2bf(lo0.w);
      a0[4] = f2bf(lo1.x); a0[5] = f2bf(lo1.y); a0[6] = f2bf(lo1.z); a0[7] = f2bf(lo1.w);
      a1[0] = f2bf(hi0.x); a1[1] = f2bf(hi0.y); a1[2] = f2bf(hi0.z); a1[3] = f2bf(hi0.w);
      a1[4] = f2bf(hi1.x); a1[5] = f2bf(hi1.y); a1[6] = f2bf(hi1.z); a1[7] = f2bf(hi1.w);
    }
    em0 = em0n; em1 = em1n;
  }

  // ---- per-chunk epilogue -> LDS (normalized bf16 matrix + offsets) ----
  {
    float lg0[4], lg1[4], iv0[4], iv1[4];
#pragma unroll
    for (int r = 0; r < 4; ++r) {
      float m0v = fmaxf(d00[r], d01[r]);
      float m1v = fmaxf(d10[r], d11[r]);
#pragma unroll
      for (int d = 8; d >= 1; d >>= 1) {
        m0v = fmaxf(m0v, __shfl_xor(m0v, d, 16));
        m1v = fmaxf(m1v, __shfl_xor(m1v, d, 16));
      }
      m0v = fmaxf(m0v, 1e-37f);
      m1v = fmaxf(m1v, 1e-37f);
      lg0[r] = __logf(m0v); iv0[r] = __builtin_amdgcn_rcpf(m0v);
      lg1[r] = __logf(m1v); iv1[r] = __builtin_amdgcn_rcpf(m1v);
    }
#pragma unroll
    for (int r = 0; r < 4; ++r) {
      Ebuf[wv][4 * q + r][n] = f2bf(d00[r] * iv0[r]);
      Ebuf[wv][4 * q + r][16 + n] = f2bf(d01[r] * iv0[r]);
      Ebuf[wv][16 + 4 * q + r][n] = f2bf(d10[r] * iv1[r]);
      Ebuf[wv][16 + 4 * q + r][16 + n] = f2bf(d11[r] * iv1[r]);
    }
    if (n == 0) {
#pragma unroll
      for (int r = 0; r < 4; ++r) {
        Obuf[wv][4 * q + r] = lg0[r];
        Obuf[wv][16 + 4 * q + r] = lg1[r];
      }
    }
    float cm = fmaxf(fmaxf(fmaxf(lg0[0], lg0[1]), fmaxf(lg0[2], lg0[3])),
                     fmaxf(fmaxf(lg1[0], lg1[1]), fmaxf(lg1[2], lg1[3])));
    cm = fmaxf(cm, __shfl_xor(cm, 16));
    cm = fmaxf(cm, __shfl_xor(cm, 32));
    if (lane == 0) Cmx[wv] = cm;
  }
  __syncthreads();

  // ---- round 1: wv0: T01 -> slot0; wv1: T23 -> slot2 ----
  if (wv < 2) {
    const int ai = 2 * wv, bi = 2 * wv + 1;
    f32x4 c00, c01, c10, c11;
    float lg0[4], lg1[4], iv0[4], iv1[4];
    combine32(&Ebuf[ai][0][0], &Ebuf[bi][0][0], Obuf[ai], Obuf[bi], Cmx[bi],
              n, q, c00, c01, c10, c11, lg0, lg1, iv0, iv1);
#pragma unroll
    for (int r = 0; r < 4; ++r) {
      Ebuf[ai][4 * q + r][n] = f2bf(c00[r] * iv0[r]);
      Ebuf[ai][4 * q + r][16 + n] = f2bf(c01[r] * iv0[r]);
      Ebuf[ai][16 + 4 * q + r][n] = f2bf(c10[r] * iv1[r]);
      Ebuf[ai][16 + 4 * q + r][16 + n] = f2bf(c11[r] * iv1[r]);
    }
    if (n == 0) {
#pragma unroll
      for (int r = 0; r < 4; ++r) {
        Obuf[ai][4 * q + r] = lg0[r];
        Obuf[ai][16 + 4 * q + r] = lg1[r];
      }
    }
    float cm = fmaxf(fmaxf(fmaxf(lg0[0], lg0[1]), fmaxf(lg0[2], lg0[3])),
                     fmaxf(fmaxf(lg1[0], lg1[1]), fmaxf(lg1[2], lg1[3])));
    cm = fmaxf(cm, __shfl_xor(cm, 16));
    cm = fmaxf(cm, __shfl_xor(cm, 32));
    if (lane == 0) Cmx[ai] = cm;
  }
  __syncthreads();

  // ---- round 2: wv0: T0123 -> global super matrix ----
  if (wv == 0) {
    f32x4 c00, c01, c10, c11;
    float lg0[4], lg1[4], iv0[4], iv1[4];
    combine32(&Ebuf[0][0][0], &Ebuf[2][0][0], Obuf[0], Obuf[2], Cmx[2],
              n, q, c00, c01, c10, c11, lg0, lg1, iv0, iv1);
    const int sup = blockIdx.x;  // = b*NSUP + s
    float* E = ecT4 + (size_t)sup * 32 * 32;
    {
      float4 s;
      s = make_float4(c00[0] * iv0[0], c00[1] * iv0[1], c00[2] * iv0[2], c00[3] * iv0[3]);
      *(float4*)&E[n * 32 + 4 * q] = s;
      s = make_float4(c10[0] * iv1[0], c10[1] * iv1[1], c10[2] * iv1[2], c10[3] * iv1[3]);
      *(float4*)&E[n * 32 + 16 + 4 * q] = s;
      s = make_float4(c01[0] * iv0[0], c01[1] * iv0[1], c01[2] * iv0[2], c01[3] * iv0[3]);
      *(float4*)&E[(16 + n) * 32 + 4 * q] = s;
      s = make_float4(c11[0] * iv1[0], c11[1] * iv1[1], c11[2] * iv1[2], c11[3] * iv1[3]);
      *(float4*)&E[(16 + n) * 32 + 16 + 4 * q] = s;
    }
    if (n == 0) {
      float* Mo = moff4 + (size_t)sup * 32;
      *(float4*)&Mo[4 * q] = make_float4(lg0[0], lg0[1], lg0[2], lg0[3]);
      *(float4*)&Mo[16 + 4 * q] = make_float4(lg1[0], lg1[1], lg1[2], lg1[3]);
    }
    float cm = fmaxf(fmaxf(fmaxf(lg0[0], lg0[1]), fmaxf(lg0[2], lg0[3])),
                     fmaxf(fmaxf(lg1[0], lg1[1]), fmaxf(lg1[2], lg1[3])));
    cm = fmaxf(cm, __shfl_xor(cm, 16));
    cm = fmaxf(cm, __shfl_xor(cm, 32));
    if (lane == 0) cmax4[sup] = cm;
  }
}

// ---------------- K3: phase-2 sweep (8 supers) + fused numerator -----------
__global__ __launch_bounds__(64) void phase2_kernel(
    const float* __restrict__ logem, const float* __restrict__ start_trans,
    const float* __restrict__ end_trans, const float* __restrict__ ecT4,
    const float* __restrict__ moff4, const float* __restrict__ cmax4,
    const float* __restrict__ trans, const int* __restrict__ tags,
    const int* __restrict__ mask, float* __restrict__ out) {
  const int b = blockIdx.x;
  const int lane = threadIdx.x;
  const int j = lane & 31;
  __shared__ __align__(16) float qlds[32];

  const int base_row = b * Ss;
  int lensum = 0;
  float snum = 0.f;
#pragma unroll
  for (int k = 0; k < 8; ++k) {
    const int ss = lane + 64 * k;
    const int m = mask[base_row + ss];
    lensum += m;
    if (m) {
      const int tg = tags[base_row + ss];
      snum += logem[(size_t)(base_row + ss) * Tt + tg];
      if (ss > 0) snum += trans[tags[base_row + ss - 1] * Tt + tg];
    }
  }
#pragma unroll
  for (int d = 32; d >= 1; d >>= 1) {
    snum += __shfl_xor(snum, d);
    lensum += __shfl_xor(lensum, d);
  }

  const float* base = ecT4 + (size_t)b * NSUP * 32 * 32;
  const float* mbase = moff4 + (size_t)b * NSUP * 32;
  const float cm_l = (j < NSUP) ? cmax4[b * NSUP + j] : 0.f;

  float4 M[8], N[8];
  const float* r0 = base + j * 32;
#pragma unroll
  for (int k = 0; k < 8; ++k) M[k] = *(const float4*)(r0 + 4 * k);
  float mo_cur = mbase[j];

  float al0 = start_trans[j] + logem[(size_t)base_row * Tt + j];
  float m0 = al0;
#pragma unroll
  for (int d = 16; d >= 1; d >>= 1) m0 = fmaxf(m0, __shfl_xor(m0, d, 32));
  float a = __expf(al0 - m0);
  float Mb = m0;
  const float eend = __expf(end_trans[j]);

  float mo_next = 0.f;
  for (int c = 0; c < NSUP; ++c) {
    if (c + 1 < NSUP) {
      const float* rn = base + ((c + 1) * 32 + j) * 32;
#pragma unroll
      for (int k = 0; k < 8; ++k) N[k] = *(const float4*)(rn + 4 * k);
      mo_next = mbase[(c + 1) * 32 + j];
    }
    const float mom = __shfl(cm_l, c, 32);   // uniform broadcast, no reduce
    const float qv = a * __expf(mo_cur - mom);
    if (lane < 32) qlds[j] = qv;
    asm volatile("s_waitcnt lgkmcnt(0)" ::: "memory");  // LDS only; ecT4
    __builtin_amdgcn_sched_barrier(0);                  // prefetch stays in flight
    float s0 = 0.f, s1 = 0.f, s2 = 0.f, s3 = 0.f;       // depth-8 chains
#pragma unroll
    for (int k = 0; k < 8; ++k) {
      const float4 q4 = *(const float4*)(qlds + 4 * k);
      float* sp = (k & 1) ? ((k & 2) ? &s3 : &s1) : ((k & 2) ? &s2 : &s0);
      *sp = fmaf(q4.x, M[k].x, *sp);
      *sp = fmaf(q4.y, M[k].y, *sp);
      *sp = fmaf(q4.z, M[k].z, *sp);
      *sp = fmaf(q4.w, M[k].w, *sp);
    }
    const float s = (s0 + s1) + (s2 + s3);
    Mb += mom;
    if ((c & 3) == 3) {        // rescale at c=3,7 (exact: skipped log factors
      float m = s;             // ride inside a until here; f32 headroom ok)
#pragma unroll
      for (int d = 16; d >= 1; d >>= 1) m = fmaxf(m, __shfl_xor(m, d, 32));
      m = fmaxf(m, 1e-30f);
      a = s * __builtin_amdgcn_rcpf(m);
      Mb += __logf(m);
    } else {
      a = s;
    }
#pragma unroll
    for (int k = 0; k < 8; ++k) M[k] = N[k];
    mo_cur = mo_next;
  }
  float z = a * eend;
#pragma unroll
  for (int d = 16; d >= 1; d >>= 1) z += __shfl_xor(z, d, 32);
  if (lane == 0) {
    const float numfull = snum + start_trans[tags[base_row]] +
                          end_trans[tags[base_row + lensum - 1]];
    const float denom = Mb + __logf(z);
    atomicAdd(out, -(numfull - denom) * (1.0f / 32.0f));
  }
}

extern "C" void kernel_launch(void* const* d_in, const int* in_sizes, int n_in,
                              void* d_out, int out_size, void* d_ws, size_t ws_size,
                              hipStream_t stream) {
  const float* hidden = (const float*)d_in[0];
  const float* W = (const float*)d_in[1];
  const float* bias = (const float*)d_in[2];
  const float* start_trans = (const float*)d_in[3];
  const float* end_trans = (const float*)d_in[4];
  const float* trans = (const float*)d_in[5];
  const int* tags = (const int*)d_in[6];
  const int* mask = (const int*)d_in[7];
  float* out = (float*)d_out;

  float* logem = (float*)d_ws;                          // 2 MB
  float* ecT4 = logem + (size_t)NROWS * Tt;             // 1 MB
  float* moff4 = ecT4 + (size_t)Bb * NSUP * 32 * 32;    // 32 KB
  float* cmax4 = moff4 + (size_t)Bb * NSUP * 32;        // 1 KB
  short* Wpk = (short*)(cmax4 + (size_t)Bb * NSUP);     // 64 KB

  wpack_kernel<<<8, 128, 0, stream>>>(W, Wpk, out);  // also zeroes out
  emis_fused_kernel<<<NROWS / 16, 256, 0, stream>>>(hidden, Wpk, bias, logem);
  chunk_kernel<<<Bb * NCHUNK / 4, 256, 0, stream>>>(logem, trans, mask,
                                                    ecT4, moff4, cmax4);
  phase2_kernel<<<Bb, 64, 0, stream>>>(logem, start_trans, end_trans, ecT4,
                                       moff4, cmax4, trans, tags, mask, out);
}